// Round 4
// baseline (432.833 us; speedup 1.0000x reference)
//
#include <hip/hip_runtime.h>
#include <hip/hip_bf16.h>

// RGCN gather-mm, etype-sorted edges.
// out[v][n] = sum_{e: dst[e]=v} sum_k feat[src[e]][k] * W[etype[e]][k][n]
//
// Per-edge MFMA GEMM. R4: ZERO workspace use — R3's first launch passed
// (absmax 1.0) but cvt_w wrote ~262KB into d_ws without checking ws_size,
// corrupting the harness's pristine input copies -> calls 2+ consistently
// wrong. Now: W staged per-block from original fp32 weight (transpose+cvt
// into LDS), segments handled via sortedness (rmin/rmax per block + A-row
// masking). Only d_out is written.

#define TM 64  // edges per block (4 waves x 16 rows)

typedef __attribute__((ext_vector_type(8))) __bf16 bf16x8;
typedef __attribute__((ext_vector_type(4))) float f32x4;

__global__ __launch_bounds__(256)
void rgcn_main(const float* __restrict__ feat, const float* __restrict__ weight,
               const int* __restrict__ src, const int* __restrict__ dst,
               const int* __restrict__ etypes, int E,
               float* __restrict__ out) {
    // Wt[n][k] bf16, k padded 128->136 (row stride 272B).
    __shared__ __bf16 Wt[64 * 136];

    int b = blockIdx.x;
    int e0 = b * TM;
    int t = threadIdx.x;
    int wave = t >> 6, lane = t & 63;
    int q = lane >> 4, m = lane & 15;          // quad, row/col-in-tile
    int wbase = e0 + wave * 16;                // this wave's first edge row

    // block-uniform relation range (etypes globally sorted)
    int last = e0 + TM - 1; if (last > E - 1) last = E - 1;
    int rmin = etypes[e0];
    int rmax = etypes[last];

    // preload this lane's A-row chunk (row m, k = ks*32 + q*8 + j), cvt bf16
    int em = wbase + m;
    bool rowok = em < E;
    int ei = rowok ? em : E - 1;
    int my_et = rowok ? etypes[em] : -1;       // -1 never matches any r
    const float* arow = feat + (long)src[ei] * 128;
    bf16x8 a[4];
    #pragma unroll
    for (int ks = 0; ks < 4; ks++) {
        float4 fa = *(const float4*)(arow + ks * 32 + q * 8);
        float4 fb = *(const float4*)(arow + ks * 32 + q * 8 + 4);
        bf16x8 v;
        v[0] = (__bf16)fa.x; v[1] = (__bf16)fa.y;
        v[2] = (__bf16)fa.z; v[3] = (__bf16)fa.w;
        v[4] = (__bf16)fb.x; v[5] = (__bf16)fb.y;
        v[6] = (__bf16)fb.z; v[7] = (__bf16)fb.w;
        a[ks] = v;
    }

    f32x4 acc0 = {0.f, 0.f, 0.f, 0.f};
    f32x4 acc1 = {0.f, 0.f, 0.f, 0.f};
    f32x4 acc2 = {0.f, 0.f, 0.f, 0.f};
    f32x4 acc3 = {0.f, 0.f, 0.f, 0.f};

    // loop over relations present in this tile (1 iter for 24985/25000 blocks)
    for (int r = rmin; r <= rmax; ++r) {
        if (r != rmin) __syncthreads();        // protect LDS before restage

        // stage W[r] (f32 [128][64]) -> Wt[n][k] bf16, packed 2k per dword.
        // p -> (n = p&63, kh = p>>6): reads coalesced over n, 16 iters/thread.
        const float* wg = weight + (r << 13);  // r*128*64
        for (int p = t; p < 4096; p += 256) {
            int n = p & 63, kh = p >> 6;
            float w0 = wg[(kh * 2) * 64 + n];
            float w1 = wg[(kh * 2 + 1) * 64 + n];
            union { unsigned u; __bf16 h[2]; } pk;
            pk.h[0] = (__bf16)w0; pk.h[1] = (__bf16)w1;
            *(unsigned*)&Wt[n * 136 + kh * 2] = pk.u;   // 4B aligned
        }
        __syncthreads();

        bool on = (my_et == r);
        #pragma unroll
        for (int ks = 0; ks < 4; ks++) {
            bf16x8 af = a[ks];
            if (!on) {
                #pragma unroll
                for (int j = 0; j < 8; j++) af[j] = (__bf16)0.f;
            }
            // B frag: lane -> B[k = ks*32+q*8+j][n = nt*16+m] from Wt[n][k]
            bf16x8 b0 = *(const bf16x8*)(&Wt[(0 * 16 + m) * 136 + ks * 32 + q * 8]);
            bf16x8 b1 = *(const bf16x8*)(&Wt[(1 * 16 + m) * 136 + ks * 32 + q * 8]);
            bf16x8 b2 = *(const bf16x8*)(&Wt[(2 * 16 + m) * 136 + ks * 32 + q * 8]);
            bf16x8 b3 = *(const bf16x8*)(&Wt[(3 * 16 + m) * 136 + ks * 32 + q * 8]);
            acc0 = __builtin_amdgcn_mfma_f32_16x16x32_bf16(af, b0, acc0, 0, 0, 0);
            acc1 = __builtin_amdgcn_mfma_f32_16x16x32_bf16(af, b1, acc1, 0, 0, 0);
            acc2 = __builtin_amdgcn_mfma_f32_16x16x32_bf16(af, b2, acc2, 0, 0, 0);
            acc3 = __builtin_amdgcn_mfma_f32_16x16x32_bf16(af, b3, acc3, 0, 0, 0);
        }
    }

    // C/D layout: col = lane&15 (m), row = q*4 + reg  [measured m89/m91]
    #pragma unroll
    for (int reg = 0; reg < 4; reg++) {
        int er = wbase + q * 4 + reg;
        if (er < E) {
            float* orow = out + (long)dst[er] * 64;
            unsafeAtomicAdd(orow + 0 * 16 + m, acc0[reg]);
            unsafeAtomicAdd(orow + 1 * 16 + m, acc1[reg]);
            unsafeAtomicAdd(orow + 2 * 16 + m, acc2[reg]);
            unsafeAtomicAdd(orow + 3 * 16 + m, acc3[reg]);
        }
    }
}

extern "C" void kernel_launch(void* const* d_in, const int* in_sizes, int n_in,
                              void* d_out, int out_size, void* d_ws, size_t ws_size,
                              hipStream_t stream) {
    const float* feat   = (const float*)d_in[0];
    const float* weight = (const float*)d_in[1];
    const int*   src    = (const int*)d_in[2];
    const int*   dst    = (const int*)d_in[3];
    const int*   etypes = (const int*)d_in[4];
    float* out = (float*)d_out;

    int E = in_sizes[2];

    // out is 0xAA-poisoned; zero-init (also covers nodes with no in-edges)
    hipMemsetAsync(d_out, 0, (size_t)out_size * sizeof(float), stream);

    int grid = (E + TM - 1) / TM;
    rgcn_main<<<grid, 256, 0, stream>>>(feat, weight, src, dst, etypes, E, out);
}